// Round 3
// baseline (52.057 us; speedup 1.0000x reference)
//
#include <hip/hip_runtime.h>
#include <hip/hip_bf16.h>
#include <math.h>

// Problem: x (64, 2, 512, 512) f32. x0 = x[:,0] -> (64,512,512).
// n[v] = sqrt(sum_{b,f} x0[b,v,f]^2)
// out[b,i,j] = (sum_f x0[b,i,f]*x0[b,j,f]) / (n[i]*n[j])   (symmetric in i,j)

#define BATCH 64
#define VDIM 512
#define FDIM 512
#define XBS (2 * VDIM * FDIM)      // x batch stride in floats (T=2)
#define OBS (VDIM * VDIM)          // out batch stride in floats

typedef __bf16 bf16x8 __attribute__((ext_vector_type(8)));
typedef __bf16 bf16x4 __attribute__((ext_vector_type(4)));
typedef float f32x4 __attribute__((ext_vector_type(4)));

#define BM 128
#define BK 64                      // bf16 elems per K-step

// ws layout: [0, 33554432): bf16 x0 copy (64*512*512); then f32 inv_n[512]
#define INVN_OFF 33554432

// global -> LDS direct copy, 16B per lane (dest is wave-uniform base + lane*16)
#define GLL16(g, l)                                                          \
    __builtin_amdgcn_global_load_lds(                                        \
        (const __attribute__((address_space(1))) void*)(g),                  \
        (__attribute__((address_space(3))) void*)(l), 16, 0, 0)

// ---------------- fused norm + bf16-convert kernel: one block per v ----------------
__global__ __launch_bounds__(512) void cvt_norm_kernel(const float* __restrict__ x,
                                                       __bf16* __restrict__ xb,
                                                       float* __restrict__ inv_n) {
    const int v = blockIdx.x;
    const int tid = threadIdx.x;
    float s = 0.f;
    const float4* xf4 = (const float4*)x;
    // 64 batches x 128 float4 per (b, v) row
    for (int c = tid; c < 8192; c += 512) {
        int b = c >> 7;
        int f4 = c & 127;
        float4 d = xf4[(size_t)b * (XBS / 4) + (size_t)v * (FDIM / 4) + f4];
        s += d.x * d.x + d.y * d.y + d.z * d.z + d.w * d.w;
        bf16x4 p;
        p[0] = (__bf16)d.x; p[1] = (__bf16)d.y; p[2] = (__bf16)d.z; p[3] = (__bf16)d.w;
        *(bf16x4*)&xb[(size_t)b * (VDIM * FDIM) + (size_t)v * FDIM + f4 * 4] = p;
    }
    #pragma unroll
    for (int off = 32; off > 0; off >>= 1) s += __shfl_down(s, off, 64);
    __shared__ float partial[8];
    if ((tid & 63) == 0) partial[tid >> 6] = s;
    __syncthreads();
    if (tid == 0) {
        float t = 0.f;
        #pragma unroll
        for (int w = 0; w < 8; ++w) t += partial[w];
        inv_n[v] = 1.0f / sqrtf(t);
    }
}

// ---------------- gram kernel: upper-triangle tiles, bf16 global_load_lds ----------------
__global__ __launch_bounds__(256) void gram_kernel(const __bf16* __restrict__ xb,
                                                   const float* __restrict__ inv_n,
                                                   float* __restrict__ out) {
    __shared__ __bf16 As[BM * BK];   // 16 KB, linear [128][64] (+XOR swizzle via src)
    __shared__ __bf16 Bs[BM * BK];

    // 64 batches x 10 upper-triangle 128x128 tiles = 640 blocks
    // XCD chunked swizzle: 640 / 8 = 80 contiguous logical wgs per XCD (~8 batches)
    const int bid = blockIdx.x;
    const int wg = (bid & 7) * 80 + (bid >> 3);
    const int batch = wg / 10;
    const int t = wg - batch * 10;
    const int TI[10] = {0, 0, 0, 0, 1, 1, 1, 2, 2, 3};
    const int TJ[10] = {0, 1, 2, 3, 1, 2, 3, 2, 3, 3};
    const int ti = TI[t];
    const int tj = TJ[t];

    const __bf16* xbb = xb + (size_t)batch * (VDIM * FDIM);
    const int tid = threadIdx.x;
    const int lane = tid & 63;
    const int wave = tid >> 6;     // 0..3
    const int wr = wave >> 1;      // 0..1
    const int wc = wave & 1;       // 0..1

    // ---- staging addresses (constant per thread; only kk advances) ----
    // chunk c = it*256 + tid in [0,1024): row = c>>3, cc = c&7
    // LDS chunk (row,cc) holds global 16B-chunk (row, cc ^ (row&7))  [both-sides XOR]
    const __bf16* gA[4];
    const __bf16* gB[4];
    __bf16* la[4];
    __bf16* lb[4];
    #pragma unroll
    for (int it = 0; it < 4; ++it) {
        int c = it * 256 + tid;
        int row = c >> 3;
        int cs = (c & 7) ^ (row & 7);
        gA[it] = xbb + (size_t)(ti * BM + row) * FDIM + cs * 8;
        gB[it] = xbb + (size_t)(tj * BM + row) * FDIM + cs * 8;
        la[it] = &As[c * 8];
        lb[it] = &Bs[c * 8];
    }

    // ---- fragment LDS byte offsets (constant per lane) ----
    // element (r, k=ks*32+(lane>>4)*8) lives at LDS chunk (r, (ks*4+(lane>>4)) ^ (r&7))
    int offA[2][4], offB[2][4];
    #pragma unroll
    for (int ks = 0; ks < 2; ++ks) {
        #pragma unroll
        for (int m = 0; m < 4; ++m) {
            int rA = wr * 64 + m * 16 + (lane & 15);
            int rB = wc * 64 + m * 16 + (lane & 15);
            int gch = ks * 4 + (lane >> 4);
            offA[ks][m] = rA * (BK * 2) + ((gch ^ (rA & 7)) * 16);
            offB[ks][m] = rB * (BK * 2) + ((gch ^ (rB & 7)) * 16);
        }
    }

    f32x4 acc[4][4];
    #pragma unroll
    for (int m = 0; m < 4; ++m)
        #pragma unroll
        for (int n = 0; n < 4; ++n)
            acc[m][n] = (f32x4){0.f, 0.f, 0.f, 0.f};

    for (int kk = 0; kk < FDIM; kk += BK) {
        #pragma unroll
        for (int it = 0; it < 4; ++it) {
            GLL16(gA[it] + kk, la[it]);
            GLL16(gB[it] + kk, lb[it]);
        }
        __syncthreads();   // compiler emits vmcnt(0) drain before barrier

        #pragma unroll
        for (int ks = 0; ks < 2; ++ks) {
            bf16x8 af[4], bfr[4];
            #pragma unroll
            for (int m = 0; m < 4; ++m) {
                af[m]  = *(const bf16x8*)((const char*)As + offA[ks][m]);
                bfr[m] = *(const bf16x8*)((const char*)Bs + offB[ks][m]);
            }
            #pragma unroll
            for (int m = 0; m < 4; ++m)
                #pragma unroll
                for (int n = 0; n < 4; ++n)
                    acc[m][n] = __builtin_amdgcn_mfma_f32_16x16x32_bf16(af[m], bfr[n], acc[m][n], 0, 0, 0);
        }
        __syncthreads();
    }

    // ---- epilogue ----
    const int rowbase = ti * BM + wr * 64;
    const int colbase = tj * BM + wc * 64;
    float* ob = out + (size_t)batch * OBS;

    // scale by inv_n[i]*inv_n[j] (symmetric) once, in registers
    float si[16], sj[4];
    #pragma unroll
    for (int m = 0; m < 4; ++m)
        #pragma unroll
        for (int q = 0; q < 4; ++q)
            si[m * 4 + q] = inv_n[rowbase + m * 16 + (lane >> 4) * 4 + q];
    #pragma unroll
    for (int n = 0; n < 4; ++n)
        sj[n] = inv_n[colbase + n * 16 + (lane & 15)];
    #pragma unroll
    for (int m = 0; m < 4; ++m)
        #pragma unroll
        for (int n = 0; n < 4; ++n)
            #pragma unroll
            for (int q = 0; q < 4; ++q)
                acc[m][n][q] *= si[m * 4 + q] * sj[n];

    // normal write: out[b][rowbase+..][colbase+..]
    #pragma unroll
    for (int n = 0; n < 4; ++n) {
        int j = colbase + n * 16 + (lane & 15);
        #pragma unroll
        for (int m = 0; m < 4; ++m)
            #pragma unroll
            for (int q = 0; q < 4; ++q) {
                int i = rowbase + m * 16 + (lane >> 4) * 4 + q;
                ob[(size_t)i * VDIM + j] = acc[m][n][q];
            }
    }

    // transposed write for off-diagonal tiles: out[b][J][I] = C[I][J]
    // wave-private LDS transpose buffer (64 rows i x 16 cols j, stride 17 f32),
    // aliased into As/Bs (dead after the K-loop; trailing barrier already passed).
    if (ti != tj) {
        float* tbase = (wave < 2) ? (float*)As : (float*)Bs;
        float* tb = tbase + (wave & 1) * 1088;   // 64*17 = 1088 f32 = 4352 B
        const int j16 = lane >> 2;               // 0..15 (slice col)
        const int ic = lane & 3;                 // 0..3  (16-wide i chunk)
        #pragma unroll
        for (int n = 0; n < 4; ++n) {
            // stage slice n (64 i x 16 j), wave-private -> no barrier needed
            #pragma unroll
            for (int m = 0; m < 4; ++m)
                #pragma unroll
                for (int q = 0; q < 4; ++q)
                    tb[(m * 16 + (lane >> 4) * 4 + q) * 17 + (lane & 15)] = acc[m][n][q];
            // read transposed, write rows of C^T as float4
            #pragma unroll
            for (int c = 0; c < 4; ++c) {
                f32x4 v4;
                #pragma unroll
                for (int e = 0; e < 4; ++e)
                    v4[e] = tb[(ic * 16 + c * 4 + e) * 17 + j16];
                int J = colbase + n * 16 + j16;
                int I = rowbase + ic * 16 + c * 4;
                *(f32x4*)&ob[(size_t)J * VDIM + I] = v4;
            }
        }
    }
}

extern "C" void kernel_launch(void* const* d_in, const int* in_sizes, int n_in,
                              void* d_out, int out_size, void* d_ws, size_t ws_size,
                              hipStream_t stream) {
    const float* x = (const float*)d_in[0];
    float* out = (float*)d_out;
    __bf16* xbf = (__bf16*)d_ws;
    float* inv_n = (float*)((char*)d_ws + INVN_OFF);

    cvt_norm_kernel<<<VDIM, 512, 0, stream>>>(x, xbf, inv_n);
    gram_kernel<<<BATCH * 10, 256, 0, stream>>>(xbf, inv_n, out);
}